// Round 7
// baseline (385.329 us; speedup 1.0000x reference)
//
#include <hip/hip_runtime.h>

// LaplacianRegularizer3D: 2 * sum over 13 forward shifts
//   S13 = {(1,0,0)} u {(dk,0,1)} u {(dk,1,dj)},  dk,dj in {-1,0,1}
// over x = f.reshape(8,12,8,256,256).
// R=2 register-marching strips (R6 structure, unchanged): one wave owns 2
// consecutive rows, all 8 k-planes in registers (wave = full 256-wide row as
// 64 x float4). Traffic = 3/2 * 201 MB ~= 302 MB.
// R7 change: launch_bounds(256,6) -> 6 waves/SIMD (24 waves/CU, was 16).
// Diagnosis: lap3d ~90us vs 48us HBM floor / 33us VALU floor => latency-bound;
// more resident waves is the lever. Liveness ~75-80 VGPR fits the ~85 cap.
// Tripwire: if WRITE_SIZE >> 0 on lap3d, the compiler spilled (R4 deja vu).

constexpr int WIDTH  = 256;
constexpr int HWs    = 256 * 256;
constexpr int NSTRIP = 8 * 12 * 256 / 2;   // 12288 strips (2 rows each)
constexpr int NBLOCK = NSTRIP / 4;         // 3072 blocks (4 waves each)

__global__ __launch_bounds__(256, 6) void lap3d(const float* __restrict__ f,
                                                float* __restrict__ partial) {
    const int tid  = threadIdx.x;
    const int lane = tid & 63;
    const int wid  = tid >> 6;
    const int ss   = blockIdx.x * 4 + wid;   // strip id
    const int bc   = ss >> 7;                // 0..95 (128 strips per image)
    const int i0   = (ss & 127) << 1;        // 0,2,...,254
    const float* base = f + (size_t)bc * 8 * HWs + (size_t)i0 * WIDTH + (size_t)lane * 4;

    const bool has_right  = (lane < 63);
    const bool has_left   = (lane > 0);
    const bool last_strip = (i0 == 254);     // wave-uniform

    float cur[8][4];
#pragma unroll
    for (int k = 0; k < 8; ++k) {
        float4 v = *reinterpret_cast<const float4*>(base + k * HWs);
        cur[k][0] = v.x; cur[k][1] = v.y; cur[k][2] = v.z; cur[k][3] = v.w;
    }

    float acc = 0.f;

#pragma unroll 1
    for (int s = 0; s < 2; ++s) {
        const bool hn = (s < 1) || !last_strip;   // wave-uniform

        // Issue next-row loads first (latency overlapped by within-row compute).
        float4 nx[8];
        if (hn) {
            const float* nb = base + (s + 1) * WIDTH;
#pragma unroll
            for (int k = 0; k < 8; ++k)
                nx[k] = *reinterpret_cast<const float4*>(nb + k * HWs);
        }

        // ---- within-row: s = (1,0,0) ----
#pragma unroll
        for (int k = 0; k < 7; ++k)
#pragma unroll
            for (int m = 0; m < 4; ++m) { float d = cur[k][m] - cur[k + 1][m]; acc += d * d; }

        // ---- within-row: s = (dk,0,1), looped by partner plane kk ----
#pragma unroll
        for (int kk = 0; kk < 8; ++kk) {
            const float e = __shfl_down(cur[kk][0], 1);  // plane kk, j0+4
#pragma unroll
            for (int k = kk - 1; k <= kk + 1; ++k) {
                if (k < 0 || k > 7) continue;
#pragma unroll
                for (int m = 0; m < 3; ++m) { float d = cur[k][m] - cur[kk][m + 1]; acc += d * d; }
                if (has_right) { float d = cur[k][3] - e; acc += d * d; }
            }
        }

        // ---- cross-row: s = (dk,1,dj), looped by partner plane kk ----
        if (hn) {
#pragma unroll
            for (int kk = 0; kk < 8; ++kk) {
                const float nr = __shfl_down(nx[kk].x, 1);  // row i+1, j0+4
                const float nl = __shfl_up(nx[kk].w, 1);    // row i+1, j0-1
                const float n0 = nx[kk].x, n1 = nx[kk].y, n2 = nx[kk].z, n3 = nx[kk].w;
#pragma unroll
                for (int k = kk - 1; k <= kk + 1; ++k) {
                    if (k < 0 || k > 7) continue;
                    // dj = 0
                    { float d = cur[k][0] - n0; acc += d * d; }
                    { float d = cur[k][1] - n1; acc += d * d; }
                    { float d = cur[k][2] - n2; acc += d * d; }
                    { float d = cur[k][3] - n3; acc += d * d; }
                    // dj = +1
                    { float d = cur[k][0] - n1; acc += d * d; }
                    { float d = cur[k][1] - n2; acc += d * d; }
                    { float d = cur[k][2] - n3; acc += d * d; }
                    if (has_right) { float d = cur[k][3] - nr; acc += d * d; }
                    // dj = -1
                    { float d = cur[k][1] - n0; acc += d * d; }
                    { float d = cur[k][2] - n1; acc += d * d; }
                    { float d = cur[k][3] - n2; acc += d * d; }
                    if (has_left) { float d = cur[k][0] - nl; acc += d * d; }
                }
            }
            // roll nxt -> cur
#pragma unroll
            for (int k = 0; k < 8; ++k) {
                cur[k][0] = nx[k].x; cur[k][1] = nx[k].y;
                cur[k][2] = nx[k].z; cur[k][3] = nx[k].w;
            }
        }
    }

    // Wave reduce, cross-wave via LDS, one partial per block (no atomics).
#pragma unroll
    for (int off = 32; off > 0; off >>= 1) acc += __shfl_down(acc, off);

    __shared__ float wsum[4];
    if (lane == 0) wsum[wid] = acc;
    __syncthreads();
    if (tid == 0) partial[blockIdx.x] = wsum[0] + wsum[1] + wsum[2] + wsum[3];
}

__global__ __launch_bounds__(256) void lap3d_reduce(const float* __restrict__ partial,
                                                    float* __restrict__ out) {
    float s = 0.f;
    for (int i = threadIdx.x; i < NBLOCK; i += 256) s += partial[i];
#pragma unroll
    for (int off = 32; off > 0; off >>= 1) s += __shfl_down(s, off);
    __shared__ float w[4];
    if ((threadIdx.x & 63) == 0) w[threadIdx.x >> 6] = s;
    __syncthreads();
    if (threadIdx.x == 0) out[0] = 2.0f * (w[0] + w[1] + w[2] + w[3]); // x2: forward shifts
}

extern "C" void kernel_launch(void* const* d_in, const int* in_sizes, int n_in,
                              void* d_out, int out_size, void* d_ws, size_t ws_size,
                              hipStream_t stream) {
    const float* f = (const float*)d_in[0];
    float* partial = (float*)d_ws;            // 3072 floats, well under ws_size
    float* out = (float*)d_out;
    lap3d<<<dim3(NBLOCK), dim3(256), 0, stream>>>(f, partial);
    lap3d_reduce<<<dim3(1), dim3(256), 0, stream>>>(partial, out);
}